// Round 1
// baseline (257.148 us; speedup 1.0000x reference)
//
#include <hip/hip_runtime.h>
#include <cstdint>
#include <cstddef>

// Problem constants
#define NUM_CODES 1024
#define DIM       256
#define NROWS     65536          // BATCH(8192) * NODE(8)
#define BM        64             // rows per tile
#define LDS_STRIDE 264           // 256 + 8 pad (16B-aligned rows, balanced banks)
#define T_TILES   4              // tiles per persistent block
#define GRID_MAIN (NROWS / BM / T_TILES)   // 256 blocks = 1 per CU
#define OUT0_ELEMS 16777216      // 8192*8*256

typedef float v4f  __attribute__((ext_vector_type(4)));
typedef __bf16 v8bf __attribute__((ext_vector_type(8)));
typedef unsigned short v8us __attribute__((ext_vector_type(8)));
typedef unsigned v2u __attribute__((ext_vector_type(2)));

__device__ inline unsigned short f2bf_rne(float f) {
  union { float f; unsigned u; } c; c.f = f;
  unsigned u = c.u;
  unsigned r = (u + 0x7FFFu + ((u >> 16) & 1u)) >> 16;
  return (unsigned short)r;
}

// packed RNE f32x2 -> bf16x2 (single HW instruction; lo -> D[15:0])
__device__ inline unsigned cvt_pk_bf16(float lo, float hi) {
  unsigned r;
  asm("v_cvt_pk_bf16_f32 %0, %1, %2" : "=v"(r) : "v"(lo), "v"(hi));
  return r;
}

// One block per code k (1024 blocks, 256 threads = one per d).
// c0[k] = 1 - ||e_k||^2/2 : used directly as the MFMA C-init so that after the
// K-loop acc = 1 + dot - ||e||^2/2 (positive, monotone in -distance).
__global__ __launch_bounds__(256) void vq_prep(const float* __restrict__ emb,
                                               unsigned short* __restrict__ eprep,
                                               float* __restrict__ c0,
                                               float* __restrict__ loss_slot) {
  const int k = blockIdx.x;
  const int d = threadIdx.x;
  float v = emb[k * DIM + d];

  float sq = v * v;
  #pragma unroll
  for (int off = 32; off; off >>= 1) sq += __shfl_down(sq, off);
  __shared__ float red[4];
  const int lane = threadIdx.x & 63, wv = threadIdx.x >> 6;
  if (lane == 0) red[wv] = sq;
  __syncthreads();
  if (threadIdx.x == 0) c0[k] = 1.0f - 0.5f * (red[0] + red[1] + red[2] + red[3]);
  if (blockIdx.x == 0 && threadIdx.x == 0) *loss_slot = 0.0f;

  // B-fragment layout for mfma_f32_16x16x32_bf16:
  // lane l holds B[kdim=(l>>4)*8+j][n=l&15]; tile = 16 codes (c16) x 32 d (kk)
  const int c16 = k >> 4;
  const int kk = d >> 5;
  const int quad = (d >> 3) & 3;
  const int j = d & 7;
  const int l = quad * 16 + (k & 15);
  eprep[(((c16 * 8 + kk) * 64) + l) * 8 + j] = f2bf_rne(v);
}

// Persistent pipelined kernel: 256 blocks x 512 threads (8 waves), T=4 tiles each.
// Per tile: [loads(t+1) issued] -> MFMA(64 codes/wave/pass, 2 passes) -> packed-u32
// argmax reduce (4-lane LDS atomicMax) -> B2 -> epilogue gather/store + stage(t+1)
// -> B3. Two barriers/tile; global loads span the compute phase so the compiler's
// vmcnt(0) drain at each barrier never stalls.
__global__ __launch_bounds__(512, 2) void vq_main(const float* __restrict__ lat,
                                                  const float* __restrict__ emb,
                                                  const unsigned short* __restrict__ eprep,
                                                  const float* __restrict__ c0arr,
                                                  float* __restrict__ out,
                                                  float* __restrict__ loss_slot) {
  __shared__ __align__(16) unsigned short xlds[2][BM * LDS_STRIDE];  // 67.6 KB dbuf
  __shared__ unsigned smax[2][BM];   // packed (score|~code) running max, dbuf
  __shared__ float lred[8];

  const int tid = threadIdx.x;
  const int lane = tid & 63;
  const int cg = tid >> 6;           // wave 0..7 = code-group (64 codes per ct-pass)
  const int lane15 = lane & 15;
  const int quad = lane >> 4;

  // Per-wave code constants, persistent across all tiles:
  // codes handled = ct*512 + cg*64 + nf*16 + lane15
  float    c0v[2][4];
  unsigned ccomp[2][4];
  #pragma unroll
  for (int ct = 0; ct < 2; ++ct)
    #pragma unroll
    for (int nf = 0; nf < 4; ++nf) {
      const int code = ct * 512 + cg * 64 + nf * 16 + lane15;
      c0v[ct][nf] = c0arr[code];
      ccomp[ct][nf] = (unsigned)(1023 - code);  // complement => ties pick lowest code under max
    }

  const v8us* __restrict__ bptr = (const v8us*)eprep;
  v4f lpart = {0.f, 0.f, 0.f, 0.f};
  v4f sreg[8];

  const size_t tbase = (size_t)blockIdx.x * T_TILES;

  // ---- prologue: stage tile 0 ----
  {
    const v4f* lp = (const v4f*)(lat + tbase * (BM * DIM));
    #pragma unroll
    for (int i = 0; i < 8; ++i) sreg[i] = __builtin_nontemporal_load(&lp[i * 512 + tid]);
  }
  if (tid < BM) smax[0][tid] = 0u;
  #pragma unroll
  for (int i = 0; i < 8; ++i) {
    const int g = i * 512 + tid, row = g >> 6, c4 = g & 63;
    v2u w;
    w.x = cvt_pk_bf16(sreg[i].x, sreg[i].y);
    w.y = cvt_pk_bf16(sreg[i].z, sreg[i].w);
    *(v2u*)(&xlds[0][row * LDS_STRIDE + c4 * 4]) = w;
  }
  __syncthreads();

  #pragma unroll 1
  for (int t = 0; t < T_TILES; ++t) {
    const int buf = t & 1;
    const unsigned short* __restrict__ xb = &xlds[buf][0];

    // issue next tile's global loads NOW; consumed after the epilogue (~4k cyc later)
    if (t + 1 < T_TILES) {
      const v4f* lp = (const v4f*)(lat + (tbase + t + 1) * (BM * DIM));
      #pragma unroll
      for (int i = 0; i < 8; ++i) sreg[i] = __builtin_nontemporal_load(&lp[i * 512 + tid]);
    }

    unsigned kmax[16];
    #pragma unroll
    for (int s = 0; s < 16; ++s) kmax[s] = 0u;

    #pragma unroll
    for (int ct = 0; ct < 2; ++ct) {
      v4f acc[4][4];
      #pragma unroll
      for (int mf = 0; mf < 4; ++mf)
        #pragma unroll
        for (int nf = 0; nf < 4; ++nf) {
          const float c = c0v[ct][nf];             // C-init = 1 - ||e||^2/2 (per col)
          acc[mf][nf] = (v4f){c, c, c, c};
        }
      #pragma unroll
      for (int kk = 0; kk < 8; ++kk) {             // D=256 in steps of 32
        v8bf b[4], a[4];
        #pragma unroll
        for (int nf = 0; nf < 4; ++nf)
          b[nf] = __builtin_bit_cast(v8bf, bptr[(((ct * 32 + cg * 4 + nf) * 8 + kk) * 64) + lane]);
        #pragma unroll
        for (int mf = 0; mf < 4; ++mf)
          a[mf] = __builtin_bit_cast(v8bf,
              *(const v8us*)(&xb[(mf * 16 + lane15) * LDS_STRIDE + kk * 32 + quad * 8]));
        #pragma unroll
        for (int mf = 0; mf < 4; ++mf)
          #pragma unroll
          for (int nf = 0; nf < 4; ++nf)
            acc[mf][nf] = __builtin_amdgcn_mfma_f32_16x16x32_bf16(a[mf], b[nf], acc[mf][nf], 0, 0, 0);
      }
      // acc in (0.67,1.33) > 0: float bits are monotone. Pack code into the low
      // 10 mantissa bits (2.4e-4 score resolution << ~4e-3 top-2 gaps).
      // 2 VALU per score: v_and_or_b32 + v_max_u32.
      #pragma unroll
      for (int nf = 0; nf < 4; ++nf) {
        const unsigned cc = ccomp[ct][nf];
        #pragma unroll
        for (int mf = 0; mf < 4; ++mf)
          #pragma unroll
          for (int i = 0; i < 4; ++i) {
            const unsigned key = (__builtin_bit_cast(unsigned, acc[mf][nf][i]) & 0xFFFFFC00u) | cc;
            const int s = mf * 4 + i;
            kmax[s] = key > kmax[s] ? key : kmax[s];
          }
      }
    }

    // reduce over the 16 lanes sharing a quad (single u32 max, no index pair)
    #pragma unroll
    for (int s = 0; s < 16; ++s) {
      #pragma unroll
      for (int mask = 1; mask <= 8; mask <<= 1) {
        const unsigned o = __shfl_xor(kmax[s], mask);
        kmax[s] = o > kmax[s] ? o : kmax[s];
      }
    }
    // cross-wave combine: 4 lanes/wave, 16 distinct rows each, 8-way contention
    if (lane15 == 0) {
      #pragma unroll
      for (int mf = 0; mf < 4; ++mf)
        #pragma unroll
        for (int i = 0; i < 4; ++i)
          atomicMax(&smax[buf][mf * 16 + quad * 4 + i], kmax[mf * 4 + i]);
    }
    __syncthreads();                               // B2: smax final, staging of t done
    if (tid < BM) smax[buf ^ 1][tid] = 0u;         // init next tile's slot (dbuf -> race-free)

    // ---- epilogue: wave cg owns rows cg*8..cg*8+7; lane covers 4 floats ----
    float* outg = out + (tbase + t) * (BM * DIM);
    #pragma unroll
    for (int j = 0; j < 8; ++j) {
      const int r = cg * 8 + j;
      const int code = (int)((~smax[buf][r]) & 1023u);
      const v4f ev = *(const v4f*)(emb + code * DIM + lane * 4);
      const v2u ls = *(const v2u*)(&xb[r * LDS_STRIDE + lane * 4]);
      v4f xv;
      xv.x = __builtin_bit_cast(float, ls.x << 16);
      xv.y = __builtin_bit_cast(float, ls.x & 0xFFFF0000u);
      xv.z = __builtin_bit_cast(float, ls.y << 16);
      xv.w = __builtin_bit_cast(float, ls.y & 0xFFFF0000u);
      __builtin_nontemporal_store(ev, (v4f*)(outg + (size_t)r * DIM + lane * 4));
      const v4f d = xv - ev;
      lpart = d * d + lpart;
    }

    // write next tile's bf16 X into the other buffer (loads issued at loop top)
    if (t + 1 < T_TILES) {
      #pragma unroll
      for (int i = 0; i < 8; ++i) {
        const int g = i * 512 + tid, row = g >> 6, c4 = g & 63;
        v2u w;
        w.x = cvt_pk_bf16(sreg[i].x, sreg[i].y);
        w.y = cvt_pk_bf16(sreg[i].z, sreg[i].w);
        *(v2u*)(&xlds[buf ^ 1][row * LDS_STRIDE + c4 * 4]) = w;
      }
    }
    __syncthreads();                               // B3: buffer ready for next MFMA
  }

  // ---- loss: one atomic per block ----
  float p = lpart.x + lpart.y + lpart.z + lpart.w;
  #pragma unroll
  for (int off = 32; off; off >>= 1) p += __shfl_down(p, off);
  if (lane == 0) lred[cg] = p;
  __syncthreads();
  if (tid == 0) {
    float s = 0.f;
    #pragma unroll
    for (int c = 0; c < 8; ++c) s += lred[c];
    atomicAdd(loss_slot, s * (1.25f / 16777216.0f));
  }
}

extern "C" void kernel_launch(void* const* d_in, const int* in_sizes, int n_in,
                              void* d_out, int out_size, void* d_ws, size_t ws_size,
                              hipStream_t stream) {
  const float* lat = (const float*)d_in[0];   // [8192, 2048] fp32
  const float* emb = (const float*)d_in[1];   // [1024, 256] fp32
  float* out = (float*)d_out;                 // [16777216] quantized_st + [1] vq_loss
  unsigned short* eprep = (unsigned short*)d_ws;                    // 512 KiB
  float* c0 = (float*)((char*)d_ws + NUM_CODES * DIM * sizeof(unsigned short));
  float* loss_slot = out + (size_t)OUT0_ELEMS;

  vq_prep<<<NUM_CODES, 256, 0, stream>>>(emb, eprep, c0, loss_slot);
  vq_main<<<GRID_MAIN, 512, 0, stream>>>(lat, emb, eprep, c0, out, loss_slot);
}